// Round 4
// baseline (4935.319 us; speedup 1.0000x reference)
//
#include <hip/hip_runtime.h>

#define T_STEPS 256
#define HH      100
#define ROWS    8
#define NMV     500    // active matvec threads (100 j-cols x 5 k-slices)
#define BLK     512

// ws float layout:
//   [0      .. 120000)  P packed weights: flat = (((m*4 + c)*5 + i)*500 + t)*4 + kk
//                       = W_m[c*100 + j][s*20 + i*4 + kk]  with t = s*100 + j
//                       m: 0=W_hh1, 1=W_ih2, 2=W_hh2
//   [120000 ..120400)   b1s = b_ih1 + b_hh1
//   [120400 ..120800)   b2s = b_ih2 + b_hh2
//   [120800 ..121200)   wis = W_ih1[:,0]
//   [121200 ..121300)   wls = W_lin[0][:]
//   [121300]            blin
#define WS_TOTAL 121301

__global__ __launch_bounds__(512) void pack_kernel(
    const float* __restrict__ Whh1, const float* __restrict__ Wih2,
    const float* __restrict__ Whh2,
    const float* __restrict__ bih1, const float* __restrict__ bhh1,
    const float* __restrict__ bih2, const float* __restrict__ bhh2,
    const float* __restrict__ Wih1, const float* __restrict__ Wlin,
    const float* __restrict__ blin, float* __restrict__ ws) {
  int idx = blockIdx.x * BLK + threadIdx.x;
  if (idx < 120000) {
    int kk = idx & 3;
    int q  = idx >> 2;          // ((m*4+c)*5+i)*500 + t
    int t  = q % 500;
    int q2 = q / 500;           // (m*4+c)*5 + i
    int i  = q2 % 5;
    int q3 = q2 / 5;            // m*4 + c
    int c  = q3 & 3;
    int m  = q3 >> 2;
    int s  = t / 100;
    int j  = t - s * 100;
    int col = c * 100 + j;      // output row of W (0..399)
    int k   = s * 20 + i * 4 + kk;  // 0..99
    const float* W = (m == 0) ? Whh1 : (m == 1) ? Wih2 : Whh2;
    ws[idx] = W[col * HH + k];
  } else if (idx < 120400) {
    int j = idx - 120000; ws[idx] = bih1[j] + bhh1[j];
  } else if (idx < 120800) {
    int j = idx - 120400; ws[idx] = bih2[j] + bhh2[j];
  } else if (idx < 121200) {
    ws[idx] = Wih1[idx - 120800];
  } else if (idx < 121300) {
    ws[idx] = Wlin[idx - 121200];
  } else if (idx == 121300) {
    ws[idx] = blin[0];
  }
}

__device__ __forceinline__ float sigf(float v) {
  return 1.0f / (1.0f + __expf(-v));
}
__device__ __forceinline__ float tanh_fast(float v) {
  float t = __expf(2.0f * v);
  return 1.0f - 2.0f / (t + 1.0f);
}
__device__ __forceinline__ void fma4(const float4 w, const float4 h, float& a) {
  a = fmaf(w.x, h.x, fmaf(w.y, h.y, fmaf(w.z, h.z, fmaf(w.w, h.w, a))));
}

__global__ __launch_bounds__(512) void lstm_persist(
    const float* __restrict__ x, const float* __restrict__ ws,
    float* __restrict__ out, int T) {
  __shared__ float gbp[5][ROWS][400];
  __shared__ __align__(16) float h1[ROWS][HH];
  __shared__ __align__(16) float h2[ROWS][HH];
  __shared__ float b1s[400], b2s[400], wis[400], wls[HH], xs[ROWS];

  const int tid = threadIdx.x;
  const int r0  = blockIdx.x * ROWS;

  // ---- init ----
  if (tid < 400) {
    b1s[tid] = ws[120000 + tid];
    b2s[tid] = ws[120400 + tid];
    wis[tid] = ws[120800 + tid];
  }
  if (tid < HH) wls[tid] = ws[121200 + tid];
#pragma unroll
  for (int p = 0; p < 2; ++p) {
    int e = tid + 512 * p;
    if (e < ROWS * HH) { (&h1[0][0])[e] = 0.0f; (&h2[0][0])[e] = 0.0f; }
  }
  if (tid < ROWS) xs[tid] = x[(r0 + tid) * T];
  __syncthreads();

  const bool mv  = (tid < NMV);
  const int  s   = tid / 100;          // k-slice 0..4
  const int  j   = tid - s * 100;      // col base 0..99
  const int  s20 = s * 20;
  const float* wp = ws + tid * 4;

  // ---- P1 (W_hh1 slice) permanently register-resident: 20 float4 ----
  float4 p1w[4][5];
  if (mv) {
#pragma unroll
    for (int g = 0; g < 4; ++g)
#pragma unroll
      for (int i = 0; i < 5; ++i)
        p1w[g][i] = *(const float4*)(wp + (g * 5 + i) * 2000);
  }

  // act-phase element assignment: pass0 -> e=tid, pass1 -> e=tid+512
  const int e0r = tid / 100, e0n = tid - e0r * 100;
  const int e1  = tid + 512;
  const int e1r = e1 / 100, e1n = e1 - e1r * 100;
  const bool a1 = (e1 < ROWS * HH);
  float c1a = 0.f, c1b = 0.f, c2a = 0.f, c2b = 0.f;

  float4 buf[4][4];   // mv2 pipeline ring: [slot][gate]

#pragma unroll 1
  for (int t = 0; t < T; ++t) {
    // ============ layer-1 matvec: W_hh1 @ h1 (register weights) ============
    if (mv) {
      // prologue prefetch for mv2: chunks 0..3 (P2, i=0..3); delivery
      // overlaps the mv1 FMA below and is drained by the phase barrier.
#pragma unroll
      for (int c = 0; c < 4; ++c)
#pragma unroll
        for (int g = 0; g < 4; ++g)
          buf[c][g] = *(const float4*)(wp + (20 + g * 5 + c) * 2000);

      float acc[4][8];
#pragma unroll
      for (int c = 0; c < 4; ++c)
#pragma unroll
        for (int r = 0; r < 8; ++r) acc[c][r] = 0.0f;
#pragma unroll
      for (int i = 0; i < 5; ++i)
#pragma unroll
        for (int r = 0; r < 8; ++r) {
          float4 h = *(const float4*)&h1[r][s20 + i * 4];
          fma4(p1w[0][i], h, acc[0][r]);
          fma4(p1w[1][i], h, acc[1][r]);
          fma4(p1w[2][i], h, acc[2][r]);
          fma4(p1w[3][i], h, acc[3][r]);
        }
#pragma unroll
      for (int c = 0; c < 4; ++c)
#pragma unroll
        for (int r = 0; r < 8; ++r) gbp[s][r][c * 100 + j] = acc[c][r];
    }
    __syncthreads();

    // ============ layer-1 activations ============
    {
      {
        float xv = xs[e0r];
        float g[4];
#pragma unroll
        for (int gg = 0; gg < 4; ++gg) {
          int jj = e0n + 100 * gg;
          float v = gbp[0][e0r][jj] + gbp[1][e0r][jj] + gbp[2][e0r][jj] +
                    gbp[3][e0r][jj] + gbp[4][e0r][jj];
          g[gg] = v + b1s[jj] + wis[jj] * xv;
        }
        float iv = sigf(g[0]), fv = sigf(g[1]);
        float gv = tanh_fast(g[2]), ov = sigf(g[3]);
        c1a = fv * c1a + iv * gv;
        h1[e0r][e0n] = ov * tanh_fast(c1a);
      }
      if (a1) {
        float xv = xs[e1r];
        float g[4];
#pragma unroll
        for (int gg = 0; gg < 4; ++gg) {
          int jj = e1n + 100 * gg;
          float v = gbp[0][e1r][jj] + gbp[1][e1r][jj] + gbp[2][e1r][jj] +
                    gbp[3][e1r][jj] + gbp[4][e1r][jj];
          g[gg] = v + b1s[jj] + wis[jj] * xv;
        }
        float iv = sigf(g[0]), fv = sigf(g[1]);
        float gv = tanh_fast(g[2]), ov = sigf(g[3]);
        c1b = fv * c1b + iv * gv;
        h1[e1r][e1n] = ov * tanh_fast(c1b);
      }
    }
    __syncthreads();

    // ============ layer-2 matvec: W_ih2 @ h1 + W_hh2 @ h2 (pipelined) ======
    if (mv) {
      float acc[4][8];
#pragma unroll
      for (int c = 0; c < 4; ++c)
#pragma unroll
        for (int r = 0; r < 8; ++r) acc[c][r] = 0.0f;

      // 10 chunks: c 0..4 = P2 (x h1), c 5..9 = P3 (x h2); slot ring of 4.
#pragma unroll
      for (int c = 0; c < 10; ++c) {
        const int slot = c & 3;
        const int ii   = (c < 5) ? c : c - 5;
#pragma unroll
        for (int r = 0; r < 8; ++r) {
          float4 h = (c < 5) ? *(const float4*)&h1[r][s20 + ii * 4]
                             : *(const float4*)&h2[r][s20 + ii * 4];
          fma4(buf[slot][0], h, acc[0][r]);
          fma4(buf[slot][1], h, acc[1][r]);
          fma4(buf[slot][2], h, acc[2][r]);
          fma4(buf[slot][3], h, acc[3][r]);
        }
        if (c + 4 < 10) {
          const int c2 = c + 4;
          const int mb = (c2 < 5) ? 20 : 40;
          const int i2 = (c2 < 5) ? c2 : c2 - 5;
#pragma unroll
          for (int g = 0; g < 4; ++g)
            buf[c2 & 3][g] = *(const float4*)(wp + (mb + g * 5 + i2) * 2000);
        }
      }
#pragma unroll
      for (int c = 0; c < 4; ++c)
#pragma unroll
        for (int r = 0; r < 8; ++r) gbp[s][r][c * 100 + j] = acc[c][r];
    }
    __syncthreads();

    // ============ layer-2 activations + x prefetch ============
    {
      {
        float g[4];
#pragma unroll
        for (int gg = 0; gg < 4; ++gg) {
          int jj = e0n + 100 * gg;
          float v = gbp[0][e0r][jj] + gbp[1][e0r][jj] + gbp[2][e0r][jj] +
                    gbp[3][e0r][jj] + gbp[4][e0r][jj];
          g[gg] = v + b2s[jj];
        }
        float iv = sigf(g[0]), fv = sigf(g[1]);
        float gv = tanh_fast(g[2]), ov = sigf(g[3]);
        c2a = fv * c2a + iv * gv;
        h2[e0r][e0n] = ov * tanh_fast(c2a);
      }
      if (a1) {
        float g[4];
#pragma unroll
        for (int gg = 0; gg < 4; ++gg) {
          int jj = e1n + 100 * gg;
          float v = gbp[0][e1r][jj] + gbp[1][e1r][jj] + gbp[2][e1r][jj] +
                    gbp[3][e1r][jj] + gbp[4][e1r][jj];
          g[gg] = v + b2s[jj];
        }
        float iv = sigf(g[0]), fv = sigf(g[1]);
        float gv = tanh_fast(g[2]), ov = sigf(g[3]);
        c2b = fv * c2b + iv * gv;
        h2[e1r][e1n] = ov * tanh_fast(c2b);
      }
    }
    if (tid < ROWS && (t + 1) < T) xs[tid] = x[(r0 + tid) * T + t + 1];
    __syncthreads();
  }

  // ============ output: out[r] = h2[r]·wlin + blin ============
  {
    int row  = tid >> 6;   // 0..7 (8 waves)
    int lane = tid & 63;
    float p = h2[row][lane] * wls[lane];
    if (lane + 64 < HH) p += h2[row][lane + 64] * wls[lane + 64];
#pragma unroll
    for (int off = 32; off > 0; off >>= 1) p += __shfl_down(p, off, 64);
    if (lane == 0) out[r0 + row] = p + ws[121300];
  }
}

// ---------------- launcher ----------------
extern "C" void kernel_launch(void* const* d_in, const int* in_sizes, int n_in,
                              void* d_out, int out_size, void* d_ws, size_t ws_size,
                              hipStream_t stream) {
  const float* x    = (const float*)d_in[0];
  const float* Wih1 = (const float*)d_in[1];
  const float* Whh1 = (const float*)d_in[2];
  const float* bih1 = (const float*)d_in[3];
  const float* bhh1 = (const float*)d_in[4];
  const float* Wih2 = (const float*)d_in[5];
  const float* Whh2 = (const float*)d_in[6];
  const float* bih2 = (const float*)d_in[7];
  const float* bhh2 = (const float*)d_in[8];
  const float* Wlin = (const float*)d_in[9];
  const float* blin = (const float*)d_in[10];

  float* ws  = (float*)d_ws;
  float* out = (float*)d_out;

  const int B = in_sizes[0] / T_STEPS;   // 2048

  pack_kernel<<<(WS_TOTAL + BLK - 1) / BLK, BLK, 0, stream>>>(
      Whh1, Wih2, Whh2, bih1, bhh1, bih2, bhh2, Wih1, Wlin, blin, ws);

  lstm_persist<<<B / ROWS, BLK, 0, stream>>>(x, ws, out, T_STEPS);
}